// Round 1
// 401.532 us; speedup vs baseline: 1.0073x; 1.0073x over previous
//
#include <hip/hip_runtime.h>
#include <math.h>

#define BB 64
#define SS 2048
#define HH 512
#define AA 128
#define MM (BB*SS)

typedef __attribute__((ext_vector_type(8)))  short short8;
typedef __attribute__((ext_vector_type(16))) float f32x16;

__device__ inline unsigned short f2bf_rne(float f) {
    unsigned u = __float_as_uint(f);
    unsigned r = (u + 0x7fff + ((u >> 16) & 1)) >> 16;
    return (unsigned short)r;
}
__device__ inline float bf2f(unsigned short h) {
    return __uint_as_float(((unsigned)h) << 16);
}
__device__ inline float fast_tanh(float x) {
    float t = __expf(2.0f * x);
    return 1.0f - 2.0f * __builtin_amdgcn_rcpf(t + 1.0f);
}

// ---------------------------------------------------------------------------
// Kernel 0: W1 [512,128] fp32 -> packed per-fragment hi/lo bf16 layout:
//   PB[it][s][nt][hilo][lane][j]  (it=k>>5, s,half from k, nt/lane from n)
// value = W1T_x[n = nt*32 + (lane&31)][k = it*32 + (s*2 + lane>>5)*8 + j]
// Each score-kernel B-fragment load becomes 64 lanes x contiguous 16 B = 1 KiB.
// ---------------------------------------------------------------------------
__global__ __launch_bounds__(256) void prep_w1t(
    const float* __restrict__ W1, unsigned short* __restrict__ PB)
{
    int id = blockIdx.x * 256 + threadIdx.x;   // 65536 = 512k x 128n
    int n = id & 127, k = id >> 7;
    float v = W1[k * AA + n];
    unsigned short h = f2bf_rne(v);
    unsigned short l = f2bf_rne(v - bf2f(h));
    int it = k >> 5, r = k & 31;
    int s = r >> 4, half = (r >> 3) & 1, j = r & 7;
    int lane = half * 32 + (n & 31);
    int nt = n >> 5;
    size_t off = ((size_t)(((it * 2 + s) * 4 + nt) * 2) * 64 + lane) * 8 + j;
    PB[off]       = h;     // hilo = 0
    PB[off + 512] = l;     // hilo = 1  (+64*8)
}

// ---------------------------------------------------------------------------
// Kernel 1: scores = tanh(X@W1+b1)@W2+b2, split-bf16 MFMA (3 products).
// v2: NO LDS, NO barriers. B fragments read directly from packed global
// layout (256 KB total, L1/L2-resident, fully coalesced). A prefetched
// one iteration ahead in registers; without __syncthreads there is no
// vmcnt(0) drain, so A loads stay in flight across iterations.
// Issue order per iter keeps younger A-prefetch from being drained by
// B waits: B(s0) -> convert(A) -> MFMA(s0) -> B(s1) -> Apre -> MFMA(s1).
// ---------------------------------------------------------------------------
__global__ __launch_bounds__(256, 2) void score_mfma(
    const float* __restrict__ X,
    const unsigned short* __restrict__ PB,
    const float* __restrict__ b1, const float* __restrict__ W2,
    const float* __restrict__ b2, float* __restrict__ scores)
{
    const int tid  = threadIdx.x;
    const int wave = tid >> 6;
    const int lane = tid & 63;
    const int l31  = lane & 31;
    const int half = lane >> 5;
    const int m0   = blockIdx.x * 256;

    const float* aptr0 = X + (size_t)(m0 + wave * 64      + l31) * HH + half * 8;
    const float* aptr1 = X + (size_t)(m0 + wave * 64 + 32 + l31) * HH + half * 8;
    const unsigned short* pbl = PB + lane * 8;

    f32x16 acc[2][4];
    #pragma unroll
    for (int mt = 0; mt < 2; mt++)
        #pragma unroll
        for (int nt = 0; nt < 4; nt++)
            #pragma unroll
            for (int j = 0; j < 16; j++) acc[mt][nt][j] = 0.f;

    float4 apre[2][2][2];   // [mt][s][j-half]
    #pragma unroll
    for (int s = 0; s < 2; s++) {
        apre[0][s][0] = *(const float4*)(aptr0 + s * 16);
        apre[0][s][1] = *(const float4*)(aptr0 + s * 16 + 4);
        apre[1][s][0] = *(const float4*)(aptr1 + s * 16);
        apre[1][s][1] = *(const float4*)(aptr1 + s * 16 + 4);
    }

    #pragma unroll 1
    for (int it = 0; it < 16; it++) {
        // ---- B fragments, s = 0 (oldest in vmcnt queue)
        short8 bh[4], bl[4];
        #pragma unroll
        for (int nt = 0; nt < 4; nt++) {
            const unsigned short* p = pbl + (size_t)((it * 2 + 0) * 4 + nt) * 1024;
            bh[nt] = *(const short8*)(p);
            bl[nt] = *(const short8*)(p + 512);
        }

        // ---- convert A fragments (consumes apre; hides B(s0) latency)
        short8 ah[2][2], al[2][2];
        #pragma unroll
        for (int mt = 0; mt < 2; mt++)
            #pragma unroll
            for (int s = 0; s < 2; s++) {
                float fs[8];
                *(float4*)&fs[0] = apre[mt][s][0];
                *(float4*)&fs[4] = apre[mt][s][1];
                #pragma unroll
                for (int j = 0; j < 8; j++) {
                    unsigned short h = f2bf_rne(fs[j]);
                    ah[mt][s][j] = (short)h;
                    float r = fs[j] - bf2f(h);
                    al[mt][s][j] = (short)(__float_as_uint(r) >> 16);
                }
            }

        // ---- MFMA s = 0
        #pragma unroll
        for (int nt = 0; nt < 4; nt++) {
            acc[0][nt] = __builtin_amdgcn_mfma_f32_32x32x16_bf16(ah[0][0], bh[nt], acc[0][nt], 0, 0, 0);
            acc[0][nt] = __builtin_amdgcn_mfma_f32_32x32x16_bf16(ah[0][0], bl[nt], acc[0][nt], 0, 0, 0);
            acc[0][nt] = __builtin_amdgcn_mfma_f32_32x32x16_bf16(al[0][0], bh[nt], acc[0][nt], 0, 0, 0);
            acc[1][nt] = __builtin_amdgcn_mfma_f32_32x32x16_bf16(ah[1][0], bh[nt], acc[1][nt], 0, 0, 0);
            acc[1][nt] = __builtin_amdgcn_mfma_f32_32x32x16_bf16(ah[1][0], bl[nt], acc[1][nt], 0, 0, 0);
            acc[1][nt] = __builtin_amdgcn_mfma_f32_32x32x16_bf16(al[1][0], bh[nt], acc[1][nt], 0, 0, 0);
        }

        // ---- B fragments, s = 1
        #pragma unroll
        for (int nt = 0; nt < 4; nt++) {
            const unsigned short* p = pbl + (size_t)((it * 2 + 1) * 4 + nt) * 1024;
            bh[nt] = *(const short8*)(p);
            bl[nt] = *(const short8*)(p + 512);
        }

        // ---- A prefetch for it+1 (youngest: B(s1) wait leaves these in flight)
        if (it < 15) {
            #pragma unroll
            for (int s = 0; s < 2; s++) {
                apre[0][s][0] = *(const float4*)(aptr0 + (it + 1) * 32 + s * 16);
                apre[0][s][1] = *(const float4*)(aptr0 + (it + 1) * 32 + s * 16 + 4);
                apre[1][s][0] = *(const float4*)(aptr1 + (it + 1) * 32 + s * 16);
                apre[1][s][1] = *(const float4*)(aptr1 + (it + 1) * 32 + s * 16 + 4);
            }
        }

        // ---- MFMA s = 1
        #pragma unroll
        for (int nt = 0; nt < 4; nt++) {
            acc[0][nt] = __builtin_amdgcn_mfma_f32_32x32x16_bf16(ah[0][1], bh[nt], acc[0][nt], 0, 0, 0);
            acc[0][nt] = __builtin_amdgcn_mfma_f32_32x32x16_bf16(ah[0][1], bl[nt], acc[0][nt], 0, 0, 0);
            acc[0][nt] = __builtin_amdgcn_mfma_f32_32x32x16_bf16(al[0][1], bh[nt], acc[0][nt], 0, 0, 0);
            acc[1][nt] = __builtin_amdgcn_mfma_f32_32x32x16_bf16(ah[1][1], bh[nt], acc[1][nt], 0, 0, 0);
            acc[1][nt] = __builtin_amdgcn_mfma_f32_32x32x16_bf16(ah[1][1], bl[nt], acc[1][nt], 0, 0, 0);
            acc[1][nt] = __builtin_amdgcn_mfma_f32_32x32x16_bf16(al[1][1], bh[nt], acc[1][nt], 0, 0, 0);
        }
    }

    // ---- epilogue: tanh + dot(W2); reduce cols across 32 lanes
    const float bb2 = b2[0];
    #pragma unroll
    for (int mt = 0; mt < 2; mt++) {
        float part[16];
        #pragma unroll
        for (int r = 0; r < 16; r++) part[r] = 0.f;
        #pragma unroll
        for (int nt = 0; nt < 4; nt++) {
            int n = nt * 32 + l31;
            float bias = b1[n];
            float w2   = W2[n];
            #pragma unroll
            for (int r = 0; r < 16; r++)
                part[r] += fast_tanh(acc[mt][nt][r] + bias) * w2;
        }
        #pragma unroll
        for (int off = 16; off > 0; off >>= 1)
            #pragma unroll
            for (int r = 0; r < 16; r++)
                part[r] += __shfl_xor(part[r], off);
        if (l31 == 0) {
            #pragma unroll
            for (int r = 0; r < 16; r++) {
                int row = (r & 3) + 8 * (r >> 2) + 4 * half;
                scores[m0 + wave * 64 + mt * 32 + row] = part[r] + bb2;
            }
        }
    }
}

// ---------------------------------------------------------------------------
// Kernel 2: exact entmax-1.5 via safeguarded Newton on
//   f(tau) = sum(max(v-tau,0)^2) - 1  (convex, decreasing, C1, |f'|>=2 at root)
// From tau0=-1, f(tau0)>=0 and convexity => monotone convergence from below;
// 14 iterations >> fp32 precision. Fused (sum d, sum d^2) block reduction.
// Also emits a compacted nonzero-index list + count for the context kernel.
// scores aliases weights output: fully read into regs before any write.
// ---------------------------------------------------------------------------
__global__ __launch_bounds__(256) void entmax_newton(
    const float* __restrict__ scores, float* __restrict__ weights,
    unsigned short* __restrict__ nzidx, int* __restrict__ nzcount)
{
    __shared__ float red[4][2];
    __shared__ int cnt;
    const int t = threadIdx.x, b = blockIdx.x;
    const int wv = t >> 6, ln = t & 63;
    const float* row = scores + (size_t)b * SS;

    float v[8];
    #pragma unroll
    for (int i = 0; i < 8; i++) v[i] = row[t + 256 * i];

    // block max
    float mx = v[0];
    #pragma unroll
    for (int i = 1; i < 8; i++) mx = fmaxf(mx, v[i]);
    #pragma unroll
    for (int off = 32; off > 0; off >>= 1) mx = fmaxf(mx, __shfl_xor(mx, off));
    if (t == 0) cnt = 0;
    if (ln == 0) red[wv][0] = mx;
    __syncthreads();
    mx = fmaxf(fmaxf(red[0][0], red[1][0]), fmaxf(red[2][0], red[3][0]));

    #pragma unroll
    for (int i = 0; i < 8; i++) v[i] = (v[i] - mx) * 0.5f;

    float tau = -1.0f;
    for (int nit = 0; nit < 14; ++nit) {
        float s1 = 0.f, s2 = 0.f;
        #pragma unroll
        for (int i = 0; i < 8; i++) {
            float d = fmaxf(v[i] - tau, 0.f);
            s1 += d;
            s2 = fmaf(d, d, s2);
        }
        #pragma unroll
        for (int off = 32; off > 0; off >>= 1) {
            s1 += __shfl_xor(s1, off);
            s2 += __shfl_xor(s2, off);
        }
        __syncthreads();                 // protect red[] reuse
        if (ln == 0) { red[wv][0] = s1; red[wv][1] = s2; }
        __syncthreads();
        s1 = red[0][0] + red[1][0] + red[2][0] + red[3][0];
        s2 = red[0][1] + red[1][1] + red[2][1] + red[3][1];
        tau += (s2 - 1.0f) / (2.0f * s1);   // Newton: tau - f/f'
    }

    #pragma unroll
    for (int i = 0; i < 8; i++) {
        float d = fmaxf(v[i] - tau, 0.f);
        weights[(size_t)b * SS + t + 256 * i] = d * d;
        if (d > 0.f) {
            int p = atomicAdd(&cnt, 1);
            nzidx[(size_t)b * SS + p] = (unsigned short)(t + 256 * i);
        }
    }
    __syncthreads();
    if (t == 0) nzcount[b] = cnt;
}

// ---------------------------------------------------------------------------
// Kernel 3: context[b,h] = sum_s X[b,s,h]*w[b,s] over the compacted support.
// Block (c,b) handles support entries e = c, c+32, ... — no dense scan.
// ---------------------------------------------------------------------------
__global__ __launch_bounds__(256) void context_kernel(
    const float* __restrict__ X, const float* __restrict__ weights,
    const unsigned short* __restrict__ nzidx, const int* __restrict__ nzcount,
    float* __restrict__ ctx)
{
    const int b = blockIdx.y;
    const int c = blockIdx.x;             // 0..31
    const int tid = threadIdx.x;
    const int n = nzcount[b];
    const unsigned short* ib = nzidx + (size_t)b * SS;
    const float* wrow = weights + (size_t)b * SS;
    float acc0 = 0.f, acc1 = 0.f;
    for (int e = c; e < n; e += 32) {
        int s = ib[e];
        float w = wrow[s];
        float2 x = *(const float2*)(X + ((size_t)b * SS + s) * HH + 2 * tid);
        acc0 = fmaf(x.x, w, acc0);
        acc1 = fmaf(x.y, w, acc1);
    }
    if (n > c) {
        atomicAdd(&ctx[b * HH + 2 * tid],     acc0);
        atomicAdd(&ctx[b * HH + 2 * tid + 1], acc1);
    }
}

// ---------------------------------------------------------------------------
extern "C" void kernel_launch(void* const* d_in, const int* in_sizes, int n_in,
                              void* d_out, int out_size, void* d_ws, size_t ws_size,
                              hipStream_t stream) {
    const float* X  = (const float*)d_in[0];   // [64,2048,512]
    const float* W1 = (const float*)d_in[1];   // [512,128]
    const float* b1 = (const float*)d_in[2];   // [128]
    const float* W2 = (const float*)d_in[3];   // [128,1]
    const float* b2 = (const float*)d_in[4];   // [1]

    float* out     = (float*)d_out;
    float* ctx     = out;                      // [64,512]
    float* weights = out + BB * HH;            // [64,2048]
    float* scores  = weights;                  // staged in weights region

    unsigned short* PB      = (unsigned short*)d_ws;            // 256 KB packed B
    unsigned short* nzidx   = PB + (size_t)AA * HH * 2;         // 256 KB
    int*            nzcount = (int*)(nzidx + (size_t)BB * SS);  // 256 B

    hipMemsetAsync(ctx, 0, (size_t)BB * HH * sizeof(float), stream);
    prep_w1t<<<dim3(256), 256, 0, stream>>>(W1, PB);
    score_mfma<<<dim3(MM / 256), 256, 0, stream>>>(X, PB, b1, W2, b2, scores);
    entmax_newton<<<dim3(BB), 256, 0, stream>>>(scores, weights, nzidx, nzcount);
    context_kernel<<<dim3(32, BB), 256, 0, stream>>>(X, weights, nzidx, nzcount, ctx);
}